// Round 7
// baseline (143.601 us; speedup 1.0000x reference)
//
#include <hip/hip_runtime.h>

// N_RNA=20000, N_PROT=5000, D=128, C=4, E=500000
#define DIM 128
#define NCLS 4
#define NBUCKET 8

typedef _Float16 f16x8 __attribute__((ext_vector_type(8)));
typedef float    f32x4 __attribute__((ext_vector_type(4)));

// ---------- fp32 -> fp16 conversion into workspace ----------
__global__ __launch_bounds__(256) void cvt_f16_kernel(
    const float* __restrict__ src, _Float16* __restrict__ dst, int n)
{
    int i = (blockIdx.x * blockDim.x + threadIdx.x) * 8;
    const int stride = gridDim.x * blockDim.x * 8;
    for (; i + 7 < n; i += stride) {
        const float4 a = *(const float4*)(src + i);
        const float4 b = *(const float4*)(src + i + 4);
        f16x8 o;
        o[0] = (_Float16)a.x; o[1] = (_Float16)a.y;
        o[2] = (_Float16)a.z; o[3] = (_Float16)a.w;
        o[4] = (_Float16)b.x; o[5] = (_Float16)b.y;
        o[6] = (_Float16)b.z; o[7] = (_Float16)b.w;
        *(f16x8*)(dst + i) = o;
    }
}

// ---------- 3-bit counting sort of edges by rna-index bucket ----------
// Pass 1: per-block histograms (exact mapping e = blk*256 + t).
__global__ __launch_bounds__(256) void hist_kernel(
    const int* __restrict__ ridx, int nE, int bdiv, int* __restrict__ blockHist)
{
    __shared__ int cnt[NBUCKET];
    if (threadIdx.x < NBUCKET) cnt[threadIdx.x] = 0;
    __syncthreads();
    const int e = blockIdx.x * 256 + threadIdx.x;
    if (e < nE) {
        int b = ridx[e] / bdiv; if (b > NBUCKET - 1) b = NBUCKET - 1;
        atomicAdd(&cnt[b], 1);
    }
    __syncthreads();
    if (threadIdx.x < NBUCKET)
        blockHist[blockIdx.x * NBUCKET + threadIdx.x] = cnt[threadIdx.x];
}

// Pass 2a: bucket totals -> exclusive bucket starts (1 block).
__global__ __launch_bounds__(256) void bucket_total_kernel(
    const int* __restrict__ blockHist, int nBlk, int* __restrict__ bucketStart)
{
    __shared__ int part[256];
    const int b = threadIdx.x & 7, i0 = threadIdx.x >> 3;
    int s = 0;
    for (int i = i0; i < nBlk; i += 32) s += blockHist[i * NBUCKET + b];
    part[threadIdx.x] = s;
    __syncthreads();
    if (threadIdx.x < NBUCKET) {
        int tot = 0;
        for (int j = 0; j < 32; ++j) tot += part[j * NBUCKET + threadIdx.x];
        part[threadIdx.x] = tot;   // each t<8 reads only {j*8+t}, writes {t}: safe
    }
    __syncthreads();
    if (threadIdx.x == 0) {
        int run = 0;
        for (int b2 = 0; b2 < NBUCKET; ++b2) { bucketStart[b2] = run; run += part[b2]; }
        bucketStart[NBUCKET] = run;
    }
}

// Pass 2b: per-(block,bucket) exclusive offsets (8 blocks, one bucket each).
__global__ __launch_bounds__(256) void block_off_kernel(
    const int* __restrict__ blockHist, int nBlk,
    const int* __restrict__ bucketStart, int* __restrict__ blockOff)
{
    __shared__ int lds[256];
    __shared__ int carry;
    const int b = blockIdx.x;
    if (threadIdx.x == 0) carry = bucketStart[b];
    __syncthreads();
    const int nChunk = (nBlk + 255) / 256;
    for (int c = 0; c < nChunk; ++c) {
        const int idx = c * 256 + threadIdx.x;
        const int h = (idx < nBlk) ? blockHist[idx * NBUCKET + b] : 0;
        lds[threadIdx.x] = h;
        __syncthreads();
        for (int off = 1; off < 256; off <<= 1) {       // Hillis-Steele inclusive
            const int v = (threadIdx.x >= (unsigned)off) ? lds[threadIdx.x - off] : 0;
            __syncthreads();
            lds[threadIdx.x] += v;
            __syncthreads();
        }
        const int incl = lds[threadIdx.x];
        const int chunkTot = lds[255];
        const int base = carry;
        __syncthreads();
        if (idx < nBlk) blockOff[idx * NBUCKET + b] = base + incl - h;
        if (threadIdx.x == 0) carry = base + chunkTot;
        __syncthreads();
    }
}

// Pass 3: scatter (ridx, pidx, e) into bucket-partitioned arrays.
__global__ __launch_bounds__(256) void scatter_kernel(
    const int* __restrict__ ridx, const int* __restrict__ pidx, int nE, int bdiv,
    const int* __restrict__ blockOff,
    int* __restrict__ sR, int* __restrict__ sP, int* __restrict__ sE)
{
    __shared__ int cnt[NBUCKET];
    if (threadIdx.x < NBUCKET) cnt[threadIdx.x] = 0;
    __syncthreads();
    const int e = blockIdx.x * 256 + threadIdx.x;
    if (e < nE) {
        const int ri = ridx[e], pi = pidx[e];
        int b = ri / bdiv; if (b > NBUCKET - 1) b = NBUCKET - 1;
        const int rank = atomicAdd(&cnt[b], 1);
        const int pos = blockOff[blockIdx.x * NBUCKET + b] + rank;
        sR[pos] = ri; sP[pos] = pi; sE[pos] = e;
    }
}

// ---------- partitioned MFMA decoder ----------
// blockIdx&7 = bucket (round-robin block->XCD puts each bucket on one XCD ->
// its 2500-row rna shard (640 KB) + prot table (1.28 MB) are L2-resident).
// A-frag: q[m=lane&15][k=quad*8+j]; D[row(edge)=quad*4+reg][col(class)=lane&15].
__global__ __launch_bounds__(256) void decoder_part_kernel(
    const _Float16* __restrict__ rna,   // [N_RNA, D] f16
    const _Float16* __restrict__ prot,  // [N_PROT, D] f16
    const int* __restrict__ sR, const int* __restrict__ sP, const int* __restrict__ sE,
    const int* __restrict__ bucketStart,   // [9]
    const float* __restrict__ wrel, const float* __restrict__ wcls,
    float* __restrict__ out, int nE)
{
    const int lane = threadIdx.x & 63;
    const int m    = lane & 15;
    const int q    = lane >> 4;

    // B fragments: wf_n[d] = sum_c wrel[c,d] * wcls[c,n], n = lane&15 (n>=4 zero)
    const float wc0 = (m < NCLS) ? wcls[0 * NCLS + m] : 0.0f;
    const float wc1 = (m < NCLS) ? wcls[1 * NCLS + m] : 0.0f;
    const float wc2 = (m < NCLS) ? wcls[2 * NCLS + m] : 0.0f;
    const float wc3 = (m < NCLS) ? wcls[3 * NCLS + m] : 0.0f;
    f16x8 bfrag[4];
#pragma unroll
    for (int t = 0; t < 4; ++t) {
        const int d0 = t * 32 + q * 8;
#pragma unroll
        for (int half = 0; half < 2; ++half) {
            const float4 r0 = *(const float4*)(wrel + 0 * DIM + d0 + half * 4);
            const float4 r1 = *(const float4*)(wrel + 1 * DIM + d0 + half * 4);
            const float4 r2 = *(const float4*)(wrel + 2 * DIM + d0 + half * 4);
            const float4 r3 = *(const float4*)(wrel + 3 * DIM + d0 + half * 4);
            bfrag[t][half * 4 + 0] = (_Float16)(wc0 * r0.x + wc1 * r1.x + wc2 * r2.x + wc3 * r3.x);
            bfrag[t][half * 4 + 1] = (_Float16)(wc0 * r0.y + wc1 * r1.y + wc2 * r2.y + wc3 * r3.y);
            bfrag[t][half * 4 + 2] = (_Float16)(wc0 * r0.z + wc1 * r1.z + wc2 * r2.z + wc3 * r3.z);
            bfrag[t][half * 4 + 3] = (_Float16)(wc0 * r0.w + wc1 * r1.w + wc2 * r2.w + wc3 * r3.w);
        }
    }

    const int bucket = blockIdx.x & (NBUCKET - 1);
    const int brank  = blockIdx.x >> 3;
    const int nBlkB  = gridDim.x >> 3;
    const int start  = bucketStart[bucket];
    const int end    = bucketStart[bucket + 1];
    const int cntB   = end - start;
    if (cntB <= 0) return;

    const int nTasks  = (cntB + 15) >> 4;
    const int waveB   = brank * 4 + ((int)threadIdx.x >> 6);
    const int nWavesB = nBlkB * 4;

    for (int task = waveB; task < nTasks; task += nWavesB) {
        const int s0 = start + (task << 4);
        int sm = s0 + m; if (sm >= end) sm = end - 1;   // tail clamp; stores guarded
        const int ri = sR[sm];
        const int pi = sP[sm];
        const _Float16* rrow = rna  + (size_t)ri * DIM + q * 8;
        const _Float16* prow = prot + (size_t)pi * DIM + q * 8;

        f32x4 acc = {0.f, 0.f, 0.f, 0.f};
#pragma unroll
        for (int t = 0; t < 4; ++t) {
            const f16x8 rv = *(const f16x8*)(rrow + t * 32);
            const f16x8 pv = *(const f16x8*)(prow + t * 32);
            acc = __builtin_amdgcn_mfma_f32_16x16x32_f16(rv * pv, bfrag[t], acc, 0, 0, 0);
        }

        if (m < NCLS) {
#pragma unroll
            for (int reg = 0; reg < 4; ++reg) {
                const int pos = s0 + q * 4 + reg;
                if (pos < end) {
                    const int ee = sE[pos];
                    out[(size_t)ee * NCLS + m] = fmaxf(acc[reg], 0.0f);
                }
            }
        }
    }
}

// ---------- fp32 fallback if workspace is too small ----------
__device__ __forceinline__ float reduce4(float b0, float b1, float b2, float b3, int lane)
{
    const bool lo1 = (lane & 1) == 0;
    float k0 = lo1 ? b0 : b2, s0 = lo1 ? b2 : b0;
    float k1 = lo1 ? b1 : b3, s1 = lo1 ? b3 : b1;
    float v0 = k0 + __shfl_xor(s0, 1, 32);
    float v1 = k1 + __shfl_xor(s1, 1, 32);
    const bool lo2 = (lane & 2) == 0;
    float k = lo2 ? v0 : v1, s = lo2 ? v1 : v0;
    float v = k + __shfl_xor(s, 2, 32);
    v += __shfl_xor(v, 4, 32);
    v += __shfl_xor(v, 8, 32);
    v += __shfl_xor(v, 16, 32);
    return v;
}

__global__ __launch_bounds__(256) void decoder_f32_kernel(
    const float* __restrict__ rna, const float* __restrict__ prot,
    const int* __restrict__ ridx, const int* __restrict__ pidx,
    const float* __restrict__ wrel, const float* __restrict__ wcls,
    float* __restrict__ out, int nEdges)
{
    const int lane32 = threadIdx.x & 31;
    const int hw     = (blockIdx.x * blockDim.x + threadIdx.x) >> 5;
    const int nhw    = (gridDim.x * blockDim.x) >> 5;
    const float4 w0 = *(const float4*)(wrel + 0 * DIM + lane32 * 4);
    const float4 w1 = *(const float4*)(wrel + 1 * DIM + lane32 * 4);
    const float4 w2 = *(const float4*)(wrel + 2 * DIM + lane32 * 4);
    const float4 w3 = *(const float4*)(wrel + 3 * DIM + lane32 * 4);
    float wc[16];
#pragma unroll
    for (int i = 0; i < 16; ++i) wc[i] = wcls[i];
    float4 wf[4];
#pragma unroll
    for (int j = 0; j < 4; ++j) {
        wf[j].x = wc[j] * w0.x + wc[4 + j] * w1.x + wc[8 + j] * w2.x + wc[12 + j] * w3.x;
        wf[j].y = wc[j] * w0.y + wc[4 + j] * w1.y + wc[8 + j] * w2.y + wc[12 + j] * w3.y;
        wf[j].z = wc[j] * w0.z + wc[4 + j] * w1.z + wc[8 + j] * w2.z + wc[12 + j] * w3.z;
        wf[j].w = wc[j] * w0.w + wc[4 + j] * w1.w + wc[8 + j] * w2.w + wc[12 + j] * w3.w;
    }
    const int cls   = ((lane32 & 1) << 1) | ((lane32 >> 1) & 1);
    const int lelem = lane32 * 4;
    for (int e = hw; e < nEdges; e += nhw) {
        const float4 r = *(const float4*)(rna  + (size_t)ridx[e] * DIM + lelem);
        const float4 p = *(const float4*)(prot + (size_t)pidx[e] * DIM + lelem);
        float qx = r.x * p.x, qy = r.y * p.y, qz = r.z * p.z, qw = r.w * p.w;
        float b0 = qx * wf[0].x + qy * wf[0].y + qz * wf[0].z + qw * wf[0].w;
        float b1 = qx * wf[1].x + qy * wf[1].y + qz * wf[1].z + qw * wf[1].w;
        float b2 = qx * wf[2].x + qy * wf[2].y + qz * wf[2].z + qw * wf[2].w;
        float b3 = qx * wf[3].x + qy * wf[3].y + qz * wf[3].z + qw * wf[3].w;
        const float v = reduce4(b0, b1, b2, b3, lane32);
        if (lane32 < 4) out[(size_t)e * NCLS + cls] = fmaxf(v, 0.0f);
    }
}

extern "C" void kernel_launch(void* const* d_in, const int* in_sizes, int n_in,
                              void* d_out, int out_size, void* d_ws, size_t ws_size,
                              hipStream_t stream) {
    const float* rna  = (const float*)d_in[0];
    const float* prot = (const float*)d_in[1];
    const int*   ridx = (const int*)d_in[2];
    const int*   pidx = (const int*)d_in[3];
    const float* wrel = (const float*)d_in[4];
    const float* wcls = (const float*)d_in[5];
    float*       out  = (float*)d_out;

    const int nRnaElems  = in_sizes[0];   // 20000*128
    const int nProtElems = in_sizes[1];   // 5000*128
    const int nEdges     = in_sizes[2];   // 500000
    const int nRna       = nRnaElems / DIM;

    const int nBlkE = (nEdges + 255) / 256;
    auto align16 = [](size_t x) { return (x + 15) & ~(size_t)15; };

    // Workspace layout
    size_t off = 0;
    const size_t o_rnaH  = off; off += align16((size_t)nRnaElems * 2);
    const size_t o_protH = off; off += align16((size_t)nProtElems * 2);
    const size_t o_sR    = off; off += align16((size_t)nEdges * 4);
    const size_t o_sP    = off; off += align16((size_t)nEdges * 4);
    const size_t o_sE    = off; off += align16((size_t)nEdges * 4);
    const size_t o_bh    = off; off += align16((size_t)nBlkE * NBUCKET * 4);
    const size_t o_bo    = off; off += align16((size_t)nBlkE * NBUCKET * 4);
    const size_t o_bs    = off; off += align16((NBUCKET + 1) * 4);

    if (ws_size >= off && nEdges >= 1 && nRna >= NBUCKET) {
        char* ws = (char*)d_ws;
        _Float16* rnaH  = (_Float16*)(ws + o_rnaH);
        _Float16* protH = (_Float16*)(ws + o_protH);
        int* sR  = (int*)(ws + o_sR);
        int* sP  = (int*)(ws + o_sP);
        int* sE  = (int*)(ws + o_sE);
        int* bh  = (int*)(ws + o_bh);
        int* bo  = (int*)(ws + o_bo);
        int* bs  = (int*)(ws + o_bs);

        const int bdiv = (nRna + NBUCKET - 1) / NBUCKET;

        const int blocksR = (nRnaElems / 8 + 255) / 256;
        hipLaunchKernelGGL(cvt_f16_kernel, dim3(blocksR), dim3(256), 0, stream,
                           rna, rnaH, nRnaElems);
        const int blocksP = (nProtElems / 8 + 255) / 256;
        hipLaunchKernelGGL(cvt_f16_kernel, dim3(blocksP), dim3(256), 0, stream,
                           prot, protH, nProtElems);

        hipLaunchKernelGGL(hist_kernel, dim3(nBlkE), dim3(256), 0, stream,
                           ridx, nEdges, bdiv, bh);
        hipLaunchKernelGGL(bucket_total_kernel, dim3(1), dim3(256), 0, stream,
                           bh, nBlkE, bs);
        hipLaunchKernelGGL(block_off_kernel, dim3(NBUCKET), dim3(256), 0, stream,
                           bh, nBlkE, bs, bo);
        hipLaunchKernelGGL(scatter_kernel, dim3(nBlkE), dim3(256), 0, stream,
                           ridx, pidx, nEdges, bdiv, bo, sR, sP, sE);

        // 1024 blocks: 128 blocks per bucket; round-robin -> bucket k on XCD k.
        hipLaunchKernelGGL(decoder_part_kernel, dim3(1024), dim3(256), 0, stream,
                           rnaH, protH, sR, sP, sE, bs, wrel, wcls, out, nEdges);
    } else {
        hipLaunchKernelGGL(decoder_f32_kernel, dim3(8192), dim3(256), 0, stream,
                           rna, prot, ridx, pidx, wrel, wcls, out, nEdges);
    }
}

// Round 8
// 105.198 us; speedup vs baseline: 1.3651x; 1.3651x over previous
//
#include <hip/hip_runtime.h>

// N_RNA=20000, N_PROT=5000, D=128, C=4, E=500000
#define DIM 128
#define NCLS 4

typedef _Float16 f16x4 __attribute__((ext_vector_type(4)));
typedef _Float16 f16x8 __attribute__((ext_vector_type(8)));

// ---------- merged fp32 -> fp16 conversion (both tables, one launch) ----------
__global__ __launch_bounds__(256) void cvt_both_kernel(
    const float* __restrict__ s1, _Float16* __restrict__ d1, int n1,
    const float* __restrict__ s2, _Float16* __restrict__ d2, int n2)
{
    // n1, n2 are multiples of 8, so an 8-group never straddles the boundary.
    const int total = n1 + n2;
    int i = (blockIdx.x * blockDim.x + threadIdx.x) * 8;
    const int stride = gridDim.x * blockDim.x * 8;
    for (; i < total; i += stride) {
        const float* s; _Float16* d; int j;
        if (i < n1) { s = s1; d = d1; j = i; }
        else        { s = s2; d = d2; j = i - n1; }
        const float4 a = *(const float4*)(s + j);
        const float4 b = *(const float4*)(s + j + 4);
        f16x8 o;
        o[0] = (_Float16)a.x; o[1] = (_Float16)a.y;
        o[2] = (_Float16)a.z; o[3] = (_Float16)a.w;
        o[4] = (_Float16)b.x; o[5] = (_Float16)b.y;
        o[6] = (_Float16)b.z; o[7] = (_Float16)b.w;
        *(f16x8*)(d + j) = o;
    }
}

// ---------- helpers ----------
// 4-partials -> 1 value/lane over 32 lanes in 6 shuffles.
// Output: lane l holds sum for class cls(l)=2*(l&1)+((l>>1)&1).
__device__ __forceinline__ float reduce4(float b0, float b1, float b2, float b3, int lane)
{
    const bool lo1 = (lane & 1) == 0;
    float k0 = lo1 ? b0 : b2, s0 = lo1 ? b2 : b0;
    float k1 = lo1 ? b1 : b3, s1 = lo1 ? b3 : b1;
    float v0 = k0 + __shfl_xor(s0, 1, 32);
    float v1 = k1 + __shfl_xor(s1, 1, 32);
    const bool lo2 = (lane & 2) == 0;
    float k = lo2 ? v0 : v1, s = lo2 ? v1 : v0;
    float v = k + __shfl_xor(s, 2, 32);
    v += __shfl_xor(v, 4, 32);
    v += __shfl_xor(v, 8, 32);
    v += __shfl_xor(v, 16, 32);
    return v;
}

// Per-edge dot against fused weights; q = r .* p elementwise (packed f16 mul).
__device__ __forceinline__ void dot_store(
    f16x4 r, f16x4 p, const float4& wf0, const float4& wf1,
    const float4& wf2, const float4& wf3, int lane, int cls,
    float* __restrict__ out, long e)
{
    const f16x4 q = r * p;                       // 2x v_pk_mul_f16
    const float qx = (float)q[0], qy = (float)q[1];
    const float qz = (float)q[2], qw = (float)q[3];
    float b0 = qx * wf0.x + qy * wf0.y + qz * wf0.z + qw * wf0.w;
    float b1 = qx * wf1.x + qy * wf1.y + qz * wf1.z + qw * wf1.w;
    float b2 = qx * wf2.x + qy * wf2.y + qz * wf2.z + qw * wf2.w;
    float b3 = qx * wf3.x + qy * wf3.y + qz * wf3.z + qw * wf3.w;
    const float v = reduce4(b0, b1, b2, b3, lane);
    if (lane < 4) out[e * NCLS + cls] = fmaxf(v, 0.0f);
}

// ---------- decoder: ILP=8 edges/half-wave, 16 row loads in flight ----------
__global__ __launch_bounds__(256, 5) void decoder_ilp8_kernel(
    const _Float16* __restrict__ rna,   // [N_RNA, D] f16
    const _Float16* __restrict__ prot,  // [N_PROT, D] f16
    const int*   __restrict__ ridx,
    const int*   __restrict__ pidx,
    const float* __restrict__ wrel,
    const float* __restrict__ wcls,
    float*       __restrict__ out,
    int nEdges)                          // requires nEdges % 8 == 0 (else fallback)
{
    const int l32 = threadIdx.x & 31;
    const int hw  = (blockIdx.x * blockDim.x + threadIdx.x) >> 5;
    const int nhw = (gridDim.x * blockDim.x) >> 5;

    // Fused weights wf_j[d] = sum_c wrel[c,d]*wcls[c,j]; lane slice d = l32*4..+3
    const float4 w0 = *(const float4*)(wrel + 0 * DIM + l32 * 4);
    const float4 w1 = *(const float4*)(wrel + 1 * DIM + l32 * 4);
    const float4 w2 = *(const float4*)(wrel + 2 * DIM + l32 * 4);
    const float4 w3 = *(const float4*)(wrel + 3 * DIM + l32 * 4);
    float wc[16];
#pragma unroll
    for (int i = 0; i < 16; ++i) wc[i] = wcls[i];
    float4 wf0, wf1, wf2, wf3;
    {
        float4* wfp[4] = {&wf0, &wf1, &wf2, &wf3};
#pragma unroll
        for (int j = 0; j < 4; ++j) {
            wfp[j]->x = wc[j] * w0.x + wc[4 + j] * w1.x + wc[8 + j] * w2.x + wc[12 + j] * w3.x;
            wfp[j]->y = wc[j] * w0.y + wc[4 + j] * w1.y + wc[8 + j] * w2.y + wc[12 + j] * w3.y;
            wfp[j]->z = wc[j] * w0.z + wc[4 + j] * w1.z + wc[8 + j] * w2.z + wc[12 + j] * w3.z;
            wfp[j]->w = wc[j] * w0.w + wc[4 + j] * w1.w + wc[8 + j] * w2.w + wc[12 + j] * w3.w;
        }
    }
    const int cls = ((l32 & 1) << 1) | ((l32 >> 1) & 1);

    const long step = (long)nhw * 8;
    long e0 = (long)hw * 8;
    if (e0 + 7 >= nEdges) return;

    // Prologue: first iteration's indices
    int4 riA = *(const int4*)(ridx + e0);
    int4 piA = *(const int4*)(pidx + e0);
    int4 riB = *(const int4*)(ridx + e0 + 4);
    int4 piB = *(const int4*)(pidx + e0 + 4);

    for (;;) {
        // ---- issue all 16 row loads back-to-back (16 outstanding vmem) ----
        const f16x4 rA0 = ((const f16x4*)(rna + (size_t)riA.x * DIM))[l32];
        const f16x4 rA1 = ((const f16x4*)(rna + (size_t)riA.y * DIM))[l32];
        const f16x4 rA2 = ((const f16x4*)(rna + (size_t)riA.z * DIM))[l32];
        const f16x4 rA3 = ((const f16x4*)(rna + (size_t)riA.w * DIM))[l32];
        const f16x4 pA0 = ((const f16x4*)(prot + (size_t)piA.x * DIM))[l32];
        const f16x4 pA1 = ((const f16x4*)(prot + (size_t)piA.y * DIM))[l32];
        const f16x4 pA2 = ((const f16x4*)(prot + (size_t)piA.z * DIM))[l32];
        const f16x4 pA3 = ((const f16x4*)(prot + (size_t)piA.w * DIM))[l32];
        const f16x4 rB0 = ((const f16x4*)(rna + (size_t)riB.x * DIM))[l32];
        const f16x4 rB1 = ((const f16x4*)(rna + (size_t)riB.y * DIM))[l32];
        const f16x4 rB2 = ((const f16x4*)(rna + (size_t)riB.z * DIM))[l32];
        const f16x4 rB3 = ((const f16x4*)(rna + (size_t)riB.w * DIM))[l32];
        const f16x4 pB0 = ((const f16x4*)(prot + (size_t)piB.x * DIM))[l32];
        const f16x4 pB1 = ((const f16x4*)(prot + (size_t)piB.y * DIM))[l32];
        const f16x4 pB2 = ((const f16x4*)(prot + (size_t)piB.z * DIM))[l32];
        const f16x4 pB3 = ((const f16x4*)(prot + (size_t)piB.w * DIM))[l32];

        // ---- next iteration's indices, in flight during the computes ----
        const long en = e0 + step;
        const bool more = (en + 7) < nEdges;
        if (more) {
            riA = *(const int4*)(ridx + en);
            piA = *(const int4*)(pidx + en);
            riB = *(const int4*)(ridx + en + 4);
            piB = *(const int4*)(pidx + en + 4);
        }

        // ---- compute + store (waits drain progressively: vmcnt(12), (8), ...) ----
        dot_store(rA0, pA0, wf0, wf1, wf2, wf3, l32, cls, out, e0 + 0);
        dot_store(rA1, pA1, wf0, wf1, wf2, wf3, l32, cls, out, e0 + 1);
        dot_store(rA2, pA2, wf0, wf1, wf2, wf3, l32, cls, out, e0 + 2);
        dot_store(rA3, pA3, wf0, wf1, wf2, wf3, l32, cls, out, e0 + 3);
        dot_store(rB0, pB0, wf0, wf1, wf2, wf3, l32, cls, out, e0 + 4);
        dot_store(rB1, pB1, wf0, wf1, wf2, wf3, l32, cls, out, e0 + 5);
        dot_store(rB2, pB2, wf0, wf1, wf2, wf3, l32, cls, out, e0 + 6);
        dot_store(rB3, pB3, wf0, wf1, wf2, wf3, l32, cls, out, e0 + 7);

        if (!more) break;
        e0 = en;
    }
}

// ---------- fp32 fallback (handles any shape / tiny workspace) ----------
__global__ __launch_bounds__(256) void decoder_f32_kernel(
    const float* __restrict__ rna, const float* __restrict__ prot,
    const int* __restrict__ ridx, const int* __restrict__ pidx,
    const float* __restrict__ wrel, const float* __restrict__ wcls,
    float* __restrict__ out, int nEdges)
{
    const int lane32 = threadIdx.x & 31;
    const int hw     = (blockIdx.x * blockDim.x + threadIdx.x) >> 5;
    const int nhw    = (gridDim.x * blockDim.x) >> 5;
    const float4 w0 = *(const float4*)(wrel + 0 * DIM + lane32 * 4);
    const float4 w1 = *(const float4*)(wrel + 1 * DIM + lane32 * 4);
    const float4 w2 = *(const float4*)(wrel + 2 * DIM + lane32 * 4);
    const float4 w3 = *(const float4*)(wrel + 3 * DIM + lane32 * 4);
    float wc[16];
#pragma unroll
    for (int i = 0; i < 16; ++i) wc[i] = wcls[i];
    float4 wf[4];
#pragma unroll
    for (int j = 0; j < 4; ++j) {
        wf[j].x = wc[j] * w0.x + wc[4 + j] * w1.x + wc[8 + j] * w2.x + wc[12 + j] * w3.x;
        wf[j].y = wc[j] * w0.y + wc[4 + j] * w1.y + wc[8 + j] * w2.y + wc[12 + j] * w3.y;
        wf[j].z = wc[j] * w0.z + wc[4 + j] * w1.z + wc[8 + j] * w2.z + wc[12 + j] * w3.z;
        wf[j].w = wc[j] * w0.w + wc[4 + j] * w1.w + wc[8 + j] * w2.w + wc[12 + j] * w3.w;
    }
    const int cls   = ((lane32 & 1) << 1) | ((lane32 >> 1) & 1);
    const int lelem = lane32 * 4;
    for (int e = hw; e < nEdges; e += nhw) {
        const float4 r = *(const float4*)(rna  + (size_t)ridx[e] * DIM + lelem);
        const float4 p = *(const float4*)(prot + (size_t)pidx[e] * DIM + lelem);
        float qx = r.x * p.x, qy = r.y * p.y, qz = r.z * p.z, qw = r.w * p.w;
        float b0 = qx * wf[0].x + qy * wf[0].y + qz * wf[0].z + qw * wf[0].w;
        float b1 = qx * wf[1].x + qy * wf[1].y + qz * wf[1].z + qw * wf[1].w;
        float b2 = qx * wf[2].x + qy * wf[2].y + qz * wf[2].z + qw * wf[2].w;
        float b3 = qx * wf[3].x + qy * wf[3].y + qz * wf[3].z + qw * wf[3].w;
        const float v = reduce4(b0, b1, b2, b3, lane32);
        if (lane32 < 4) out[(size_t)e * NCLS + cls] = fmaxf(v, 0.0f);
    }
}

extern "C" void kernel_launch(void* const* d_in, const int* in_sizes, int n_in,
                              void* d_out, int out_size, void* d_ws, size_t ws_size,
                              hipStream_t stream) {
    const float* rna  = (const float*)d_in[0];
    const float* prot = (const float*)d_in[1];
    const int*   ridx = (const int*)d_in[2];
    const int*   pidx = (const int*)d_in[3];
    const float* wrel = (const float*)d_in[4];
    const float* wcls = (const float*)d_in[5];
    float*       out  = (float*)d_out;

    const int nRnaElems  = in_sizes[0];   // 20000*128
    const int nProtElems = in_sizes[1];   // 5000*128
    const int nEdges     = in_sizes[2];   // 500000

    const size_t rnaBytes  = (size_t)nRnaElems * 2;
    const size_t needBytes = rnaBytes + (size_t)nProtElems * 2;

    if (ws_size >= needBytes && (nEdges % 8) == 0 && nEdges >= 8 &&
        (nRnaElems % 8) == 0 && (nProtElems % 8) == 0) {
        _Float16* rnaH  = (_Float16*)d_ws;
        _Float16* protH = (_Float16*)((char*)d_ws + rnaBytes);

        const int totalElems = nRnaElems + nProtElems;
        const int cvtBlocks  = (totalElems / 8 + 255) / 256;
        hipLaunchKernelGGL(cvt_both_kernel, dim3(cvtBlocks), dim3(256), 0, stream,
                           rna, rnaH, nRnaElems, prot, protH, nProtElems);

        // 2048 blocks = 8 blocks/CU queued; occupancy-capped ~20 waves/CU
        // (launch_bounds(256,5)); each half-wave ~3.8 iterations of 8 edges.
        hipLaunchKernelGGL(decoder_ilp8_kernel, dim3(2048), dim3(256), 0, stream,
                           rnaH, protH, ridx, pidx, wrel, wcls, out, nEdges);
    } else {
        hipLaunchKernelGGL(decoder_f32_kernel, dim3(8192), dim3(256), 0, stream,
                           rna, prot, ridx, pidx, wrel, wcls, out, nEdges);
    }
}